// Round 1
// baseline (349.452 us; speedup 1.0000x reference)
//
#include <hip/hip_runtime.h>

// Problem dims (fixed by setup_inputs)
#define BATCH 4
#define HH 128
#define WW 128
#define CC 128
#define BIN 64
#define NPIX (BATCH * HH * WW)   // 65536

// ---------------------------------------------------------------------------
// Kernel 1: 1x1 conv == GEMM  Y[p][d] = sum_c X[p][c] * W[c][d]
// Block: 256 threads, tile = 64 pixels x 128 out-channels, K chunked by 32.
// blockIdx.y selects (main, W_main) vs (ref, W_ref).
// ---------------------------------------------------------------------------
__global__ __launch_bounds__(256, 4)
void conv1x1_kernel(const float* __restrict__ Xm, const float* __restrict__ Xr,
                    const float* __restrict__ Wm, const float* __restrict__ Wr,
                    float* __restrict__ Ym, float* __restrict__ Yr) {
    const float* __restrict__ X = blockIdx.y ? Xr : Xm;
    const float* __restrict__ W = blockIdx.y ? Wr : Wm;
    float* __restrict__ Y       = blockIdx.y ? Yr : Ym;

    __shared__ float Xs[32][64];    // [c][p] transposed, 8 KB
    __shared__ float Ws[32][128];   // [c][d], 16 KB

    const int t      = threadIdx.x;
    const int p_base = blockIdx.x * 64;
    const int tx = t & 15;          // d-group: 16 groups of 8 channels
    const int ty = t >> 4;          // p-group: 16 groups of 4 pixels
    const int d0 = tx * 8;
    const int p0 = ty * 4;

    // X-staging assignment: 64 threads cover pixels, 4 groups cover 8 c each
    const int lp = t & 63;
    const int lc = (t >> 6) * 8;

    float acc[4][8];
#pragma unroll
    for (int i = 0; i < 4; ++i)
#pragma unroll
        for (int j = 0; j < 8; ++j) acc[i][j] = 0.0f;

    for (int kc = 0; kc < CC; kc += 32) {
        __syncthreads();
        // stage X chunk (transposed)
        const float* xrow = &X[(size_t)(p_base + lp) * CC + kc + lc];
        float4 xa = *(const float4*)(xrow);
        float4 xb = *(const float4*)(xrow + 4);
        Xs[lc + 0][lp] = xa.x; Xs[lc + 1][lp] = xa.y;
        Xs[lc + 2][lp] = xa.z; Xs[lc + 3][lp] = xa.w;
        Xs[lc + 4][lp] = xb.x; Xs[lc + 5][lp] = xb.y;
        Xs[lc + 6][lp] = xb.z; Xs[lc + 7][lp] = xb.w;
        // stage W chunk (as-is, coalesced float4)
#pragma unroll
        for (int r = 0; r < 4; ++r) {
            int off = r * 1024 + t * 4;
            *(float4*)(&Ws[0][0] + off) = *(const float4*)(W + (size_t)kc * CC + off);
        }
        __syncthreads();

#pragma unroll 8
        for (int c = 0; c < 32; ++c) {
            float4 xv  = *(const float4*)&Xs[c][p0];
            float4 wv0 = *(const float4*)&Ws[c][d0];
            float4 wv1 = *(const float4*)&Ws[c][d0 + 4];
            float xs[4] = {xv.x, xv.y, xv.z, xv.w};
            float ws[8] = {wv0.x, wv0.y, wv0.z, wv0.w, wv1.x, wv1.y, wv1.z, wv1.w};
#pragma unroll
            for (int i = 0; i < 4; ++i)
#pragma unroll
                for (int j = 0; j < 8; ++j) acc[i][j] += xs[i] * ws[j];
        }
    }

#pragma unroll
    for (int i = 0; i < 4; ++i) {
        float4 o0 = {acc[i][0], acc[i][1], acc[i][2], acc[i][3]};
        float4 o1 = {acc[i][4], acc[i][5], acc[i][6], acc[i][7]};
        float* yrow = &Y[(size_t)(p_base + p0 + i) * CC + d0];
        *(float4*)(yrow)     = o0;
        *(float4*)(yrow + 4) = o1;
    }
}

// ---------------------------------------------------------------------------
// Kernel 2: local 5x5 attention. One wave (64 lanes) per pixel.
// Lane l holds q channels {l, l+64}; logits via shfl_xor butterfly; lane = BIN
// channel for the value mix. OOB neighbors: logit 0, value 0 (zero padding).
// ---------------------------------------------------------------------------
__global__ __launch_bounds__(256, 4)
void attn_kernel(const float* __restrict__ qm,   // conv_main [NPIX][128]
                 const float* __restrict__ kr,   // conv_ref  [NPIX][128]
                 const float* __restrict__ vv,   // ref_value [NPIX][64]
                 float* __restrict__ out) {      // [NPIX][64]
    const int wave = (int)((blockIdx.x * blockDim.x + threadIdx.x) >> 6);
    const int lane = threadIdx.x & 63;
    if (wave >= NPIX) return;

    const int b  = wave >> 14;        // / (128*128)
    const int hw = wave & 16383;
    const int h  = hw >> 7;
    const int w  = hw & 127;

    const float* qp = qm + (size_t)wave * CC;
    const float q0 = qp[lane];
    const float q1 = qp[lane + 64];

    float logit[25];
#pragma unroll
    for (int kk = 0; kk < 25; ++kk) {
        const int ki = kk / 5 - 2;
        const int kj = kk % 5 - 2;
        const int hh = h + ki;
        const int ww = w + kj;
        const bool valid = ((unsigned)hh < (unsigned)HH) && ((unsigned)ww < (unsigned)WW);
        float part = 0.0f;
        if (valid) {  // wave-uniform branch
            const float* kp = kr + (((size_t)(b * HH + hh)) * WW + ww) * CC;
            part = q0 * kp[lane] + q1 * kp[lane + 64];
        }
#pragma unroll
        for (int s = 1; s < 64; s <<= 1) part += __shfl_xor(part, s, 64);
        logit[kk] = part;
    }

    // softmax over 25 (redundant per lane, in registers)
    float m = logit[0];
#pragma unroll
    for (int kk = 1; kk < 25; ++kk) m = fmaxf(m, logit[kk]);
    float s = 0.0f;
#pragma unroll
    for (int kk = 0; kk < 25; ++kk) {
        logit[kk] = __expf(logit[kk] - m);
        s += logit[kk];
    }
    const float inv = 1.0f / s;

    // value mix: lane == BIN channel
    float acc = 0.0f;
#pragma unroll
    for (int kk = 0; kk < 25; ++kk) {
        const int ki = kk / 5 - 2;
        const int kj = kk % 5 - 2;
        const int hh = h + ki;
        const int ww = w + kj;
        const bool valid = ((unsigned)hh < (unsigned)HH) && ((unsigned)ww < (unsigned)WW);
        if (valid) {
            acc += logit[kk] * vv[(((size_t)(b * HH + hh)) * WW + ww) * BIN + lane];
        }
    }
    out[(size_t)wave * BIN + lane] = acc * inv;
}

extern "C" void kernel_launch(void* const* d_in, const int* in_sizes, int n_in,
                              void* d_out, int out_size, void* d_ws, size_t ws_size,
                              hipStream_t stream) {
    const float* main_in   = (const float*)d_in[0];
    const float* ref_in    = (const float*)d_in[1];
    const float* ref_value = (const float*)d_in[2];
    const float* W_main    = (const float*)d_in[3];
    const float* W_ref     = (const float*)d_in[4];
    float* out = (float*)d_out;

    float* conv_main = (float*)d_ws;                         // 32 MB
    float* conv_ref  = conv_main + (size_t)NPIX * CC;        // 32 MB

    dim3 gconv(NPIX / 64, 2);
    conv1x1_kernel<<<gconv, 256, 0, stream>>>(main_in, ref_in, W_main, W_ref,
                                              conv_main, conv_ref);

    // 4 waves per block -> 4 consecutive pixels per block (L1/L2 locality)
    attn_kernel<<<NPIX / 4, 256, 0, stream>>>(conv_main, conv_ref, ref_value, out);
}

// Round 2
// 273.608 us; speedup vs baseline: 1.2772x; 1.2772x over previous
//
#include <hip/hip_runtime.h>

// Problem dims (fixed by setup_inputs)
#define BATCH 4
#define HH 128
#define WW 128
#define CC 128
#define BIN 64
#define NPIX (BATCH * HH * WW)   // 65536

// ---------------------------------------------------------------------------
// Kernel 1: 1x1 conv == GEMM  Y[p][d] = sum_c X[p][c] * W[c][d]
// Block: 256 threads, tile = 128 pixels x 128 out-channels, K chunked by 32.
// 8x8 register blocking: 4 ds_read_b128 per 64 FMA (DS pipe ~= VALU pipe).
// blockIdx.y selects (main, W_main) vs (ref, W_ref).
// ---------------------------------------------------------------------------
#define XS_PAD 132   // 128 + 4: keeps float4 alignment, breaks bank conflicts
__global__ __launch_bounds__(256, 3)
void conv1x1_kernel(const float* __restrict__ Xm, const float* __restrict__ Xr,
                    const float* __restrict__ Wm, const float* __restrict__ Wr,
                    float* __restrict__ Ym, float* __restrict__ Yr) {
    const float* __restrict__ X = blockIdx.y ? Xr : Xm;
    const float* __restrict__ W = blockIdx.y ? Wr : Wm;
    float* __restrict__ Y       = blockIdx.y ? Yr : Ym;

    __shared__ float Xs[32][XS_PAD];   // [c][px] transposed
    __shared__ float Ws[32][XS_PAD];   // [c][d]

    const int t      = threadIdx.x;
    const int p_base = blockIdx.x * 128;

    const int tx = t & 15;          // d-group
    const int ty = t >> 4;          // px-group
    const int d0 = tx * 8;
    const int p0 = ty * 8;

    // staging assignments
    const int xr = t >> 3;          // pixel sub-index 0..31
    const int xc = (t & 7) * 4;     // c offset 0,4,..,28
    const int wr = t >> 5;          // W row sub 0..7
    const int wc = (t & 31) * 4;    // W col 0..124

    float acc[8][8];
#pragma unroll
    for (int i = 0; i < 8; ++i)
#pragma unroll
        for (int j = 0; j < 8; ++j) acc[i][j] = 0.0f;

    for (int kc = 0; kc < CC; kc += 32) {
        __syncthreads();
        // stage X chunk, transposed to [c][px]
#pragma unroll
        for (int r = 0; r < 4; ++r) {
            const int px = xr + 32 * r;
            float4 v = *(const float4*)&X[(size_t)(p_base + px) * CC + kc + xc];
            Xs[xc + 0][px] = v.x;
            Xs[xc + 1][px] = v.y;
            Xs[xc + 2][px] = v.z;
            Xs[xc + 3][px] = v.w;
        }
        // stage W chunk [c][d]
#pragma unroll
        for (int r = 0; r < 4; ++r) {
            const int c = wr + 8 * r;
            *(float4*)&Ws[c][wc] = *(const float4*)&W[(size_t)(kc + c) * CC + wc];
        }
        __syncthreads();

#pragma unroll 8
        for (int c = 0; c < 32; ++c) {
            float4 xa = *(const float4*)&Xs[c][p0];
            float4 xb = *(const float4*)&Xs[c][p0 + 4];
            float4 wa = *(const float4*)&Ws[c][d0];
            float4 wb = *(const float4*)&Ws[c][d0 + 4];
            float xs[8] = {xa.x, xa.y, xa.z, xa.w, xb.x, xb.y, xb.z, xb.w};
            float ws[8] = {wa.x, wa.y, wa.z, wa.w, wb.x, wb.y, wb.z, wb.w};
#pragma unroll
            for (int i = 0; i < 8; ++i)
#pragma unroll
                for (int j = 0; j < 8; ++j) acc[i][j] += xs[i] * ws[j];
        }
    }

#pragma unroll
    for (int i = 0; i < 8; ++i) {
        float* yrow = &Y[(size_t)(p_base + p0 + i) * CC + d0];
        float4 o0 = {acc[i][0], acc[i][1], acc[i][2], acc[i][3]};
        float4 o1 = {acc[i][4], acc[i][5], acc[i][6], acc[i][7]};
        *(float4*)(yrow)     = o0;
        *(float4*)(yrow + 4) = o1;
    }
}

// ---------------------------------------------------------------------------
// Kernel 2: local 5x5 attention, fused logits+softmax+value-mix.
// 4 lanes per pixel: lane = (local_pixel<<2) | c_group. Each c_group owns 32
// of the 128 q/k channels -> 2-step shfl_xor reduction (within lane quad).
// One wave = 16 pixels. Value mix: each lane owns 16 of the 64 BIN channels.
// OOB neighbors contribute logit 0 (zero padding) and value 0, matching ref.
// ---------------------------------------------------------------------------
__global__ __launch_bounds__(256, 4)
void attn_kernel(const float* __restrict__ qm,   // conv_main [NPIX][128]
                 const float* __restrict__ kr,   // conv_ref  [NPIX][128]
                 const float* __restrict__ vv,   // ref_value [NPIX][64]
                 float* __restrict__ out) {      // [NPIX][64]
    const int t   = threadIdx.x;
    const int lp  = t >> 2;          // local pixel 0..63
    const int cg  = t & 3;           // channel group 0..3
    const int pix = blockIdx.x * 64 + lp;

    const int b = pix >> 14;
    const int h = (pix >> 7) & 127;
    const int w = pix & 127;

    // q channels cg*32 .. cg*32+31
    float4 q[8];
    {
        const float4* qp = (const float4*)(qm + (size_t)pix * CC + cg * 32);
#pragma unroll
        for (int j = 0; j < 8; ++j) q[j] = qp[j];
    }

    float logit[25];
#pragma unroll
    for (int ki = 0; ki < 5; ++ki) {
        const int hh = h + ki - 2;                      // wave-uniform
        const bool rowok = (unsigned)hh < (unsigned)HH;
#pragma unroll
        for (int kj = 0; kj < 5; ++kj) {
            const int ww = w + kj - 2;
            const bool valid = rowok && ((unsigned)ww < (unsigned)WW);
            float part = 0.0f;
            if (valid) {
                const float4* kp = (const float4*)(
                    kr + (((size_t)(b * HH + hh)) * WW + ww) * CC + cg * 32);
#pragma unroll
                for (int j = 0; j < 8; ++j) {
                    float4 kv = kp[j];
                    part += q[j].x * kv.x + q[j].y * kv.y +
                            q[j].z * kv.z + q[j].w * kv.w;
                }
            }
            part += __shfl_xor(part, 1, 64);
            part += __shfl_xor(part, 2, 64);
            logit[ki * 5 + kj] = part;
        }
    }

    // softmax over 25 (redundant per lane quad, in registers)
    float m = logit[0];
#pragma unroll
    for (int kk = 1; kk < 25; ++kk) m = fmaxf(m, logit[kk]);
    float s = 0.0f;
#pragma unroll
    for (int kk = 0; kk < 25; ++kk) {
        logit[kk] = __expf(logit[kk] - m);
        s += logit[kk];
    }
    const float inv = 1.0f / s;

    // value mix: lane owns BIN channels cg*16 .. cg*16+15
    float4 acc[4];
#pragma unroll
    for (int j = 0; j < 4; ++j) acc[j] = make_float4(0.f, 0.f, 0.f, 0.f);

#pragma unroll
    for (int ki = 0; ki < 5; ++ki) {
        const int hh = h + ki - 2;
        const bool rowok = (unsigned)hh < (unsigned)HH;
#pragma unroll
        for (int kj = 0; kj < 5; ++kj) {
            const int ww = w + kj - 2;
            const bool valid = rowok && ((unsigned)ww < (unsigned)WW);
            if (valid) {
                const float wgt = logit[ki * 5 + kj];
                const float4* vp = (const float4*)(
                    vv + (((size_t)(b * HH + hh)) * WW + ww) * BIN + cg * 16);
#pragma unroll
                for (int j = 0; j < 4; ++j) {
                    float4 v = vp[j];
                    acc[j].x += wgt * v.x;
                    acc[j].y += wgt * v.y;
                    acc[j].z += wgt * v.z;
                    acc[j].w += wgt * v.w;
                }
            }
        }
    }

    float4* op = (float4*)(out + (size_t)pix * BIN + cg * 16);
#pragma unroll
    for (int j = 0; j < 4; ++j) {
        float4 o = {acc[j].x * inv, acc[j].y * inv, acc[j].z * inv, acc[j].w * inv};
        op[j] = o;
    }
}

extern "C" void kernel_launch(void* const* d_in, const int* in_sizes, int n_in,
                              void* d_out, int out_size, void* d_ws, size_t ws_size,
                              hipStream_t stream) {
    const float* main_in   = (const float*)d_in[0];
    const float* ref_in    = (const float*)d_in[1];
    const float* ref_value = (const float*)d_in[2];
    const float* W_main    = (const float*)d_in[3];
    const float* W_ref     = (const float*)d_in[4];
    float* out = (float*)d_out;

    float* conv_main = (float*)d_ws;                         // 32 MB
    float* conv_ref  = conv_main + (size_t)NPIX * CC;        // 32 MB

    dim3 gconv(NPIX / 128, 2);
    conv1x1_kernel<<<gconv, 256, 0, stream>>>(main_in, ref_in, W_main, W_ref,
                                              conv_main, conv_ref);

    attn_kernel<<<NPIX / 64, 256, 0, stream>>>(conv_main, conv_ref, ref_value, out);
}